// Round 9
// baseline (129945.447 us; speedup 1.0000x reference)
//
#include <hip/hip_runtime.h>
#include <cstdint>
#include <cstddef>

#define LSTM_D  512
#define LSTM_4D 2048
#define LSTM_L  32768
#define REC_G   64               // workgroups; each owns 8 d-indices
#define REC_DPW 8
#define N_REPL  8                // h-buffer replicas (channel spreading)

typedef float f32x4 __attribute__((ext_vector_type(4)));  // native v4f32 for asm "v"

// Workspace layout:
//   ws +      0 : hb, 8 replicas x (2 buffers x 256 f32x4) = 64 KB
//                 replica r, buffer B, flit j at hb[r*512 + B*256 + j]
//                 flit = {h[2j], h[2j+1], tag, 0}
//   ws +  65536 : cbuf (512 f) c carry between chunk launches
//   ws + 131072 : wpack (64 wg * 4096 float4 = 4 MB) swizzled Wh
//   ws + 131072 + 4 MB : xbuf (C*2048 f) x-projection chunk
#define WS_CBUF_OFF  65536
#define WS_WPACK_OFF 131072
#define WS_XBUF_OFF  (131072 + (size_t)REC_G * 4096 * sizeof(float4))

// ---------------------------------------------------------------------------
// GEMM: xbuf[C][2048] = xs_chunk[C][512] @ Wi[512][2048] + b
// ---------------------------------------------------------------------------
__global__ __launch_bounds__(256)
void gemm_xproj(const float* __restrict__ A,
                const float* __restrict__ B,
                const float* __restrict__ bias,
                float* __restrict__ C)
{
    __shared__ float As[16][64];
    __shared__ float Bs[16][64];
    const int tid  = threadIdx.x;
    const int row0 = blockIdx.y * 64;
    const int col0 = blockIdx.x * 64;
    const int tx   = tid & 15;
    const int ty   = tid >> 4;
    const int lr   = tid >> 2;
    const int lk4  = (tid & 3) * 4;
    const int bk   = tid >> 4;
    const int bc4  = (tid & 15) * 4;

    float acc[4][4] = {};

    for (int k0 = 0; k0 < LSTM_D; k0 += 16) {
        float4 av = *(const float4*)(A + (size_t)(row0 + lr) * LSTM_D + k0 + lk4);
        float4 bv = *(const float4*)(B + (size_t)(k0 + bk) * LSTM_4D + col0 + bc4);
        __syncthreads();
        As[lk4 + 0][lr] = av.x;
        As[lk4 + 1][lr] = av.y;
        As[lk4 + 2][lr] = av.z;
        As[lk4 + 3][lr] = av.w;
        *(float4*)(&Bs[bk][bc4]) = bv;
        __syncthreads();
#pragma unroll
        for (int k = 0; k < 16; ++k) {
            float4 a4 = *(const float4*)(&As[k][ty * 4]);
            float4 b4 = *(const float4*)(&Bs[k][tx * 4]);
            acc[0][0] = fmaf(a4.x, b4.x, acc[0][0]);
            acc[0][1] = fmaf(a4.x, b4.y, acc[0][1]);
            acc[0][2] = fmaf(a4.x, b4.z, acc[0][2]);
            acc[0][3] = fmaf(a4.x, b4.w, acc[0][3]);
            acc[1][0] = fmaf(a4.y, b4.x, acc[1][0]);
            acc[1][1] = fmaf(a4.y, b4.y, acc[1][1]);
            acc[1][2] = fmaf(a4.y, b4.z, acc[1][2]);
            acc[1][3] = fmaf(a4.y, b4.w, acc[1][3]);
            acc[2][0] = fmaf(a4.z, b4.x, acc[2][0]);
            acc[2][1] = fmaf(a4.z, b4.y, acc[2][1]);
            acc[2][2] = fmaf(a4.z, b4.z, acc[2][2]);
            acc[2][3] = fmaf(a4.z, b4.w, acc[2][3]);
            acc[3][0] = fmaf(a4.w, b4.x, acc[3][0]);
            acc[3][1] = fmaf(a4.w, b4.y, acc[3][1]);
            acc[3][2] = fmaf(a4.w, b4.z, acc[3][2]);
            acc[3][3] = fmaf(a4.w, b4.w, acc[3][3]);
        }
    }

    float4 bb = *(const float4*)(bias + col0 + tx * 4);
#pragma unroll
    for (int i = 0; i < 4; ++i) {
        float4 o;
        o.x = acc[i][0] + bb.x;
        o.y = acc[i][1] + bb.y;
        o.z = acc[i][2] + bb.z;
        o.w = acc[i][3] + bb.w;
        *(float4*)(C + (size_t)(row0 + ty * 4 + i) * LSTM_4D + col0 + tx * 4) = o;
    }
}

// ---------------------------------------------------------------------------
// Swizzled Wh pack (see lstm_rec layout comment).
// ---------------------------------------------------------------------------
__global__ __launch_bounds__(256)
void pack_wh(const float* __restrict__ Wh, float4* __restrict__ wp)
{
    const int wg  = blockIdx.x;
    const int tid = threadIdx.x;
    for (int s = 0; s < 16; ++s) {
        const int gidx  = s * 256 + tid;
        const int wave  = gidx >> 10;
        const int lane  = (gidx >> 4) & 63;
        const int mphys = gidx & 15;
        const int m     = mphys ^ (lane & 15);
        const int g     = m >> 2;
        const int gi    = m & 3;
        const int p     = lane >> 1;
        const int d     = wg * REC_DPW + wave * 2 + (lane & 1);
        const int k     = p * 16 + gi * 4;
        float4 v;
        v.x = Wh[(size_t)(k + 0) * LSTM_4D + g * LSTM_D + d];
        v.y = Wh[(size_t)(k + 1) * LSTM_4D + g * LSTM_D + d];
        v.z = Wh[(size_t)(k + 2) * LSTM_4D + g * LSTM_D + d];
        v.w = Wh[(size_t)(k + 3) * LSTM_4D + g * LSTM_D + d];
        wp[(size_t)wg * 4096 + gidx] = v;
    }
}

// ---------------------------------------------------------------------------
// Init tagged h replicas: block r inits replica r. Buffer 1 = h0 with tag -1
// (step 0 reads buffer (0-1)&1 = 1 expecting tag -1); buffer 0 tag = -2.
// ---------------------------------------------------------------------------
__global__ void init_h(const float* __restrict__ h0, f32x4* __restrict__ hb)
{
    const int r = blockIdx.x;             // replica 0..7
    const int j = threadIdx.x;            // 0..255
    f32x4 a; a.x = h0[2 * j]; a.y = h0[2 * j + 1]; a.z = -1.0f; a.w = 0.0f;
    f32x4 z; z.x = 0.0f;      z.y = 0.0f;          z.z = -2.0f; z.w = 0.0f;
    hb[r * 512 + 256 + j] = a;
    hb[r * 512 + j]       = z;
}

// ---------------------------------------------------------------------------
// Coherent 16B VMEM primitives (sc0 sc1 = device-coherent, bypass L1/L2).
// issue8: fire 8 tag-loads, NO wait. claim9/claim0: the s_waitcnt, taking hp
// as "+v" so no use can be scheduled before the wait.
// ---------------------------------------------------------------------------
__device__ inline void issue8(const f32x4* p, f32x4 h[8])
{
    asm volatile(
        "global_load_dwordx4 %0, %8, off sc0 sc1\n\t"
        "global_load_dwordx4 %1, %8, off offset:16 sc0 sc1\n\t"
        "global_load_dwordx4 %2, %8, off offset:32 sc0 sc1\n\t"
        "global_load_dwordx4 %3, %8, off offset:48 sc0 sc1\n\t"
        "global_load_dwordx4 %4, %8, off offset:64 sc0 sc1\n\t"
        "global_load_dwordx4 %5, %8, off offset:80 sc0 sc1\n\t"
        "global_load_dwordx4 %6, %8, off offset:96 sc0 sc1\n\t"
        "global_load_dwordx4 %7, %8, off offset:112 sc0 sc1"
        : "=&v"(h[0]), "=&v"(h[1]), "=&v"(h[2]), "=&v"(h[3]),
          "=&v"(h[4]), "=&v"(h[5]), "=&v"(h[6]), "=&v"(h[7])
        : "v"(p)
        : "memory");
}

// After issue8 we issue exactly 9 more VMEM ops (4 publish + 1 out + 4 xp):
// vmcnt(9) retires precisely the 8 tag-loads, WITHOUT waiting for store acks.
__device__ inline void claim9(f32x4 h[8])
{
    asm volatile("s_waitcnt vmcnt(9)"
        : "+v"(h[0]), "+v"(h[1]), "+v"(h[2]), "+v"(h[3]),
          "+v"(h[4]), "+v"(h[5]), "+v"(h[6]), "+v"(h[7])
        :: "memory");
}

__device__ inline void claim0(f32x4 h[8])
{
    asm volatile("s_waitcnt vmcnt(0)"
        : "+v"(h[0]), "+v"(h[1]), "+v"(h[2]), "+v"(h[3]),
          "+v"(h[4]), "+v"(h[5]), "+v"(h[6]), "+v"(h[7])
        :: "memory");
}

__device__ inline void store_cohere(f32x4* p, f32x4 v)
{
    asm volatile("global_store_dwordx4 %0, %1, off sc0 sc1"
                 :: "v"(p), "v"(v) : "memory");
}

// ---------------------------------------------------------------------------
// Barrier-free persistent recurrent kernel, software-pipelined VMEM window:
// per step, issue next-step tag-loads FIRST (right after the reduce), then
// publish stores + out store + next-step xp loads, then claim with vmcnt(9)
// so the tag check never serializes on publish-store acknowledgement (the
// round-8 bottleneck: the spin's vmcnt(0) drained our own just-issued
// stores, ~1 coherent RTT on the critical path every step).
// ---------------------------------------------------------------------------
__global__ __launch_bounds__(256, 1)
void lstm_rec(const float4* __restrict__ wp,
              const float* __restrict__ xp,    // chunk's [steps][2048]
              const float* __restrict__ c0,
              float* __restrict__ out,
              f32x4* __restrict__ hb,          // 8 x 2 x 256 tagged pairs
              float* __restrict__ cbuf,        // 512 floats
              int t0, int steps)
{
    __shared__ float4 W[4096];                 // exactly 64 KB

    const int wg   = blockIdx.x;
    const int tid  = threadIdx.x;
    const int wave = tid >> 6;
    const int lane = tid & 63;
    const int p    = lane >> 1;
    const int d    = wg * REC_DPW + wave * 2 + (lane & 1);
    const int d0   = wg * REC_DPW + wave * 2;  // wave's first d
    const int mybase = wave * 1024 + lane * 16;
    const int lx   = lane & 15;
    const int fj   = wg * 4 + wave;            // this wave's flit index
    const int myrep = wg & 7;                  // consumer replica

    // One-time LDS weight fill (coalesced 64 KB copy), the only barrier.
#pragma unroll
    for (int s = 0; s < 16; ++s)
        W[s * 256 + tid] = wp[(size_t)wg * 4096 + s * 256 + tid];
    __syncthreads();

    float c_val = 0.f;
    if (lane < 2) c_val = (t0 == 0) ? c0[d] : cbuf[d];

    // Publish destinations for this wave's flit (lanes 0/1 handle 4 each).
    f32x4* pub0 = hb + (size_t)((lane & 1) * 4 + 0) * 512 + fj;  // + (t&1)*256
    f32x4* pub1 = hb + (size_t)((lane & 1) * 4 + 1) * 512 + fj;
    f32x4* pub2 = hb + (size_t)((lane & 1) * 4 + 2) * 512 + fj;
    f32x4* pub3 = hb + (size_t)((lane & 1) * 4 + 3) * 512 + fj;

    int dead = 0;

    // ---- Prologue: spin-in h(t0-1) and xp row 0. ----
    f32x4 hp[8];
    {
        const float exp_tag = (float)(t0 - 1);
        const f32x4* src = hb + myrep * 512 + ((t0 + 1) & 1) * 256 + p * 8;
        int tries = 0;
        for (;;) {
            issue8(src, hp);
            claim0(hp);
            bool ok = (hp[0].z == exp_tag) & (hp[1].z == exp_tag) &
                      (hp[2].z == exp_tag) & (hp[3].z == exp_tag) &
                      (hp[4].z == exp_tag) & (hp[5].z == exp_tag) &
                      (hp[6].z == exp_tag) & (hp[7].z == exp_tag);
            if (__ballot(ok) == ~0ull) break;
            if (++tries > (1 << 16)) { dead = 1; break; }
        }
    }
    float xpi = 0.f, xpf = 0.f, xpg = 0.f, xpo = 0.f;
    if (lane < 2) {
        const float* row = xp + d;
        xpi = row[0];
        xpf = row[LSTM_D];
        xpg = row[2 * LSTM_D];
        xpo = row[3 * LSTM_D];
    }

    for (int ts = 0; ts < steps; ++ts) {
        const int t = t0 + ts;

        float h[16];
#pragma unroll
        for (int j = 0; j < 8; ++j) {
            h[2 * j]     = hp[j].x;
            h[2 * j + 1] = hp[j].y;
        }

        // FMA from LDS weights (xor-swizzled, bank-uniform).
        float a0 = 0.f, a1 = 0.f, a2 = 0.f, a3 = 0.f;
#pragma unroll
        for (int gi = 0; gi < 4; ++gi) {
            float4 w0 = W[mybase + ((0 * 4 + gi) ^ lx)];
            float4 w1 = W[mybase + ((1 * 4 + gi) ^ lx)];
            float4 w2 = W[mybase + ((2 * 4 + gi) ^ lx)];
            float4 w3 = W[mybase + ((3 * 4 + gi) ^ lx)];
            const float h0v = h[gi * 4 + 0], h1v = h[gi * 4 + 1];
            const float h2v = h[gi * 4 + 2], h3v = h[gi * 4 + 3];
            a0 = fmaf(h0v, w0.x, a0); a0 = fmaf(h1v, w0.y, a0);
            a0 = fmaf(h2v, w0.z, a0); a0 = fmaf(h3v, w0.w, a0);
            a1 = fmaf(h0v, w1.x, a1); a1 = fmaf(h1v, w1.y, a1);
            a1 = fmaf(h2v, w1.z, a1); a1 = fmaf(h3v, w1.w, a1);
            a2 = fmaf(h0v, w2.x, a2); a2 = fmaf(h1v, w2.y, a2);
            a2 = fmaf(h2v, w2.z, a2); a2 = fmaf(h3v, w2.w, a2);
            a3 = fmaf(h0v, w3.x, a3); a3 = fmaf(h1v, w3.y, a3);
            a3 = fmaf(h2v, w3.z, a3); a3 = fmaf(h3v, w3.w, a3);
        }

        // Reduce over p (lane bits 1..5).
#pragma unroll
        for (int m = 2; m <= 32; m <<= 1) {
            a0 += __shfl_xor(a0, m, 64);
            a1 += __shfl_xor(a1, m, 64);
            a2 += __shfl_xor(a2, m, 64);
            a3 += __shfl_xor(a3, m, 64);
        }

        // ---- VMEM window: 8 tag-loads FIRST (earliest possible sample),
        //      then exactly 9 more VMEM ops, then claim vmcnt(9). ----
        const f32x4* nsrc = hb + myrep * 512 + (t & 1) * 256 + p * 8;
        issue8(nsrc, hp);                                   // +8 loads

        float hval = 0.f;
        if (lane < 2) {
            float yi = xpi + a0;
            float yf = xpf + a1;
            float yg = xpg + a2;
            float yo = xpo + a3;
            float si = 1.f / (1.f + __expf(-yi));
            float sf = 1.f / (1.f + __expf(-yf));
            float so = 1.f / (1.f + __expf(-yo));
            float tg = tanhf(yg);
            c_val = fmaf(sf, c_val, si * tg);
            hval  = so * tanhf(c_val);
        }
        const float h_other = __shfl_xor(hval, 1, 64);      // partner d's h

        if (lane < 2) {                                     // +4 stores
            f32x4 pub;
            pub.x = (lane == 0) ? hval : h_other;
            pub.y = (lane == 0) ? h_other : hval;
            pub.z = (float)t;
            pub.w = 0.0f;
            const int boff = (t & 1) * 256;
            store_cohere(pub0 + boff, pub);
            store_cohere(pub1 + boff, pub);
            store_cohere(pub2 + boff, pub);
            store_cohere(pub3 + boff, pub);
        }

        if (lane == 0)                                      // +1 store
            *(float2*)(out + (size_t)t * LSTM_D + d0) = make_float2(hval, h_other);

        const int ts1 = (ts + 1 < steps) ? (ts + 1) : ts;   // +4 loads (xp)
        float xqi = 0.f, xqf = 0.f, xqg = 0.f, xqo = 0.f;
        if (lane < 2) {
            const float* row = xp + (size_t)ts1 * LSTM_4D + d;
            xqi = row[0];
            xqf = row[LSTM_D];
            xqg = row[2 * LSTM_D];
            xqo = row[3 * LSTM_D];
        }

        claim9(hp);   // retires exactly the 8 tag-loads; store acks unfenced

        // Tag spin for step t+1 (expects tag t in buffer t&1).
        const float exp_tag = (float)t;
        int tries = 0;
        for (;;) {
            bool ok = (hp[0].z == exp_tag) & (hp[1].z == exp_tag) &
                      (hp[2].z == exp_tag) & (hp[3].z == exp_tag) &
                      (hp[4].z == exp_tag) & (hp[5].z == exp_tag) &
                      (hp[6].z == exp_tag) & (hp[7].z == exp_tag);
            if (dead || (__ballot(ok) == ~0ull)) break;
            if (++tries > (1 << 16)) { dead = 1; break; }
            issue8(nsrc, hp);
            claim0(hp);
        }

        xpi = xqi; xpf = xqf; xpg = xqg; xpo = xqo;
    }

    if (lane < 2) cbuf[d] = c_val;   // c carry for next chunk launch
}

// ---------------------------------------------------------------------------
extern "C" void kernel_launch(void* const* d_in, const int* in_sizes, int n_in,
                              void* d_out, int out_size, void* d_ws, size_t ws_size,
                              hipStream_t stream)
{
    const float* xs = (const float*)d_in[0];   // [L, 512]
    const float* Wi = (const float*)d_in[1];   // [512, 2048]
    const float* Wh = (const float*)d_in[2];   // [512, 2048]
    const float* b  = (const float*)d_in[3];   // [2048]
    const float* c0 = (const float*)d_in[4];   // [512]
    const float* h0 = (const float*)d_in[5];   // [512]
    float* out = (float*)d_out;                // [L, 512]

    uint8_t* ws = (uint8_t*)d_ws;
    f32x4*  hb    = (f32x4*)ws;
    float*  cbuf  = (float*)(ws + WS_CBUF_OFF);
    float4* wpack = (float4*)(ws + WS_WPACK_OFF);
    float*  xbuf  = (float*)(ws + WS_XBUF_OFF);

    // Largest power-of-two chunk whose xbuf fits in the workspace.
    int C = LSTM_L;
    while (C > 64 &&
           WS_XBUF_OFF + (size_t)C * LSTM_4D * sizeof(float) > ws_size)
        C >>= 1;

    init_h<<<N_REPL, 256, 0, stream>>>(h0, hb);
    pack_wh<<<REC_G, 256, 0, stream>>>(Wh, wpack);

    const int nChunks = LSTM_L / C;
    for (int k = 0; k < nChunks; ++k) {
        dim3 ggrid(LSTM_4D / 64, C / 64);
        gemm_xproj<<<ggrid, 256, 0, stream>>>(xs + (size_t)k * C * LSTM_D,
                                              Wi, b, xbuf);
        lstm_rec<<<REC_G, 256, 0, stream>>>(wpack, xbuf, c0, out,
                                            hb, cbuf, k * C, C);
    }
}